// Round 2
// baseline (1639.707 us; speedup 1.0000x reference)
//
#include <hip/hip_runtime.h>
#include <hip/hip_bf16.h>

#define B_ 8
#define N_ 4096
#define T_ 512
#define M_ 4096
#define KVB 32
#define NBLK 64
#define KSTR 520   // f16 elems per Ks row: 512 + 8 pad (16B-aligned rows, bank-staggered)
#define PSTR 48    // f16 elems per Ps row: 32 + 16 pad

typedef _Float16 f16;
typedef __attribute__((ext_vector_type(8))) f16 f16x8;
typedef __attribute__((ext_vector_type(4))) f16 f16x4;
typedef __attribute__((ext_vector_type(4))) float f32x4;

// Block = 64 query rows (n), 8 waves.
// S^T[m][n] = sum_t K[t][m]*Q[n][t] via mfma(A=Kfrag, B=Qfrag) so softmax
// rows are lane-local. Precision: q split into fp16 hi+lo, K fp16 hi only:
// S = qh*kh + ql*kh  (error ~ q*(k-kh) ~ 2^-12 rel per product).
// Wave roles: ms = w&1 owns m-half [ms*16,ms*16+16) of the 32-wide K tile;
//             ng = w>>1 owns n-cols [ng*16, ng*16+16) for softmax state.
// PV: wave w owns t-slice [w*64,(w+1)*64) x all 64 n  (O^T accumulate).
__global__ __launch_bounds__(512, 2) void fattn(
    const float* __restrict__ Qg, const float* __restrict__ Kg,
    const float* __restrict__ Vg, float* __restrict__ Og)
{
  __shared__ __align__(16) f16 Ks[KVB * KSTR];   // [m][t] fp16 (padded rows)
  __shared__ __align__(16) f16 Vs[T_ * KVB];     // [t][m] fp16, swz m^((t&3)<<3)
  __shared__ __align__(16) f16 Ps[NBLK * PSTR];  // [n][m] fp16 (padded rows)
  __shared__ float redmax[2][NBLK];
  __shared__ float redsum[2][NBLK];
  __shared__ float stat_al[NBLK];
  __shared__ float stat_il[NBLK];

  const int bid  = blockIdx.x;
  const int b    = bid >> 6;
  const int nb   = (bid & 63) << 6;   // 64-row n-tile base
  const int tid  = threadIdx.x;
  const int w    = tid >> 6;
  const int lane = tid & 63;
  const int l15  = lane & 15;
  const int lq   = lane >> 4;
  const int ms   = w & 1;
  const int ng   = w >> 1;

  // ---- Q fragments (fp16 hi+lo). B-operand: col n = ng*16+l15, k = ks*32+lq*8+j
  f16x8 qh[16], ql[16];
  {
    const float* qrow = Qg + (size_t)(b * N_ + nb + ng * 16 + l15) * T_;
    #pragma unroll
    for (int ks = 0; ks < 16; ++ks) {
      const int k0 = ks * 32 + lq * 8;
      float f[8];
      *reinterpret_cast<float4*>(&f[0]) = *reinterpret_cast<const float4*>(qrow + k0);
      *reinterpret_cast<float4*>(&f[4]) = *reinterpret_cast<const float4*>(qrow + k0 + 4);
      f16x8 h, l;
      #pragma unroll
      for (int j = 0; j < 8; ++j) {
        h[j] = (f16)f[j];
        l[j] = (f16)(f[j] - (float)h[j]);
      }
      qh[ks] = h; ql[ks] = l;
    }
  }

  // O^T accumulator: [tf][nf], row t = w*64+tf*16+lq*4+reg, col n = nf*16+l15
  f32x4 oacc[4][4];
  #pragma unroll
  for (int tf = 0; tf < 4; ++tf)
    #pragma unroll
    for (int nf = 0; nf < 4; ++nf)
      oacc[tf][nf] = f32x4{0.f, 0.f, 0.f, 0.f};

  float m_run = -INFINITY;
  float l_run = 0.f;

  for (int mt = 0; mt < M_ / KVB; ++mt) {
    const int m0 = mt * KVB;

    // ---- stage K transposed: Ks[m][t] = fp16(Kg[b][t][m0+m]); 4096 tasks
    #pragma unroll
    for (int r = 0; r < 8; ++r) {
      const int task = r * 512 + tid;
      const int m  = task & 31;
      const int t0 = (task >> 5) << 2;
      const float* src = Kg + (size_t)(b * T_ + t0) * M_ + m0 + m;
      f16x4 kk;
      kk[0] = (f16)src[0];
      kk[1] = (f16)src[M_];
      kk[2] = (f16)src[2 * M_];
      kk[3] = (f16)src[3 * M_];
      *reinterpret_cast<f16x4*>(&Ks[m * KSTR + t0]) = kk;
    }
    // ---- stage V: Vs[t][m] = fp16(Vg[b][t][m0+m]); 2048 tasks
    #pragma unroll
    for (int r = 0; r < 4; ++r) {
      const int idx = r * 512 + tid;
      const int t  = idx >> 2;
      const int mc = (idx & 3) << 3;
      const float* src = Vg + (size_t)(b * T_ + t) * M_ + m0 + mc;
      const float4 f0 = *reinterpret_cast<const float4*>(src);
      const float4 f1 = *reinterpret_cast<const float4*>(src + 4);
      f16x8 v8;
      v8[0] = (f16)f0.x; v8[1] = (f16)f0.y; v8[2] = (f16)f0.z; v8[3] = (f16)f0.w;
      v8[4] = (f16)f1.x; v8[5] = (f16)f1.y; v8[6] = (f16)f1.z; v8[7] = (f16)f1.w;
      *reinterpret_cast<f16x8*>(&Vs[t * KVB + (mc ^ ((t & 3) << 3))]) = v8;
    }
    __syncthreads();

    // ---- S^T: sacc[reg] = S[m = ms*16+lq*4+reg][n = ng*16+l15]
    f32x4 sacc = f32x4{0.f, 0.f, 0.f, 0.f};
    {
      const int abase = (ms * 16 + l15) * KSTR + lq * 8;
      #pragma unroll
      for (int ks = 0; ks < 16; ++ks) {
        const f16x8 a = *reinterpret_cast<const f16x8*>(&Ks[abase + ks * 32]);
        sacc = __builtin_amdgcn_mfma_f32_16x16x32_f16(a, qh[ks], sacc, 0, 0, 0);
        sacc = __builtin_amdgcn_mfma_f32_16x16x32_f16(a, ql[ks], sacc, 0, 0, 0);
      }
    }

    // ---- online softmax, split across the 2 ms-waves per n-group
    const int n = ng * 16 + l15;
    float tmax = fmaxf(fmaxf(sacc[0], sacc[1]), fmaxf(sacc[2], sacc[3]));
    tmax = fmaxf(tmax, __shfl_xor(tmax, 16));
    tmax = fmaxf(tmax, __shfl_xor(tmax, 32));
    if (lane < 16) redmax[ms][ng * 16 + lane] = tmax;
    __syncthreads();

    const float gmax = fmaxf(redmax[0][n], redmax[1][n]);
    const float mnew = fmaxf(m_run, gmax);
    const float alpha = __expf(m_run - mnew);   // first tile: exp(-inf) = 0
    if (ms == 0 && lane < 16) stat_al[ng * 16 + lane] = alpha;
    const float p0 = __expf(sacc[0] - mnew);
    const float p1 = __expf(sacc[1] - mnew);
    const float p2 = __expf(sacc[2] - mnew);
    const float p3 = __expf(sacc[3] - mnew);
    float psum = (p0 + p1) + (p2 + p3);
    psum += __shfl_xor(psum, 16);
    psum += __shfl_xor(psum, 32);
    if (lane < 16) redsum[ms][ng * 16 + lane] = psum;
    {
      f16x4 pk;
      pk[0] = (f16)p0; pk[1] = (f16)p1; pk[2] = (f16)p2; pk[3] = (f16)p3;
      *reinterpret_cast<f16x4*>(&Ps[n * PSTR + ms * 16 + lq * 4]) = pk;
    }
    __syncthreads();

    l_run = l_run * alpha + redsum[0][n] + redsum[1][n];
    m_run = mnew;

    // ---- PV: rescale O^T by alpha[n], then O^T[t][n] += V[t][m] * P^T[m][n]
    #pragma unroll
    for (int nf = 0; nf < 4; ++nf) {
      const float av = stat_al[nf * 16 + l15];
      #pragma unroll
      for (int tf = 0; tf < 4; ++tf) {
        oacc[tf][nf][0] *= av;
        oacc[tf][nf][1] *= av;
        oacc[tf][nf][2] *= av;
        oacc[tf][nf][3] *= av;
      }
    }
    {
      f16x8 vfr[4];
      #pragma unroll
      for (int tf = 0; tf < 4; ++tf) {
        const int t = w * 64 + tf * 16 + l15;
        vfr[tf] = *reinterpret_cast<const f16x8*>(&Vs[t * KVB + ((lq * 8) ^ ((t & 3) << 3))]);
      }
      #pragma unroll
      for (int nf = 0; nf < 4; ++nf) {
        const f16x8 pfr = *reinterpret_cast<const f16x8*>(&Ps[(nf * 16 + l15) * PSTR + lq * 8]);
        #pragma unroll
        for (int tf = 0; tf < 4; ++tf)
          oacc[tf][nf] = __builtin_amdgcn_mfma_f32_16x16x32_f16(vfr[tf], pfr, oacc[tf][nf], 0, 0, 0);
      }
    }
    __syncthreads();
  }

  // ---- epilogue: O[b][n][t] = O^T[t][n] / l[n]
  if (ms == 0 && lane < 16) stat_il[ng * 16 + lane] = 1.0f / l_run;
  __syncthreads();
  #pragma unroll
  for (int nf = 0; nf < 4; ++nf) {
    const float il = stat_il[nf * 16 + l15];
    const size_t base = (size_t)(b * N_ + nb + nf * 16 + l15) * T_;
    #pragma unroll
    for (int tf = 0; tf < 4; ++tf) {
      const int t = w * 64 + tf * 16 + lq * 4;
      float4 o;
      o.x = oacc[tf][nf][0] * il;
      o.y = oacc[tf][nf][1] * il;
      o.z = oacc[tf][nf][2] * il;
      o.w = oacc[tf][nf][3] * il;
      *reinterpret_cast<float4*>(Og + base + t) = o;
    }
  }
}

extern "C" void kernel_launch(void* const* d_in, const int* in_sizes, int n_in,
                              void* d_out, int out_size, void* d_ws, size_t ws_size,
                              hipStream_t stream) {
  const float* Q = (const float*)d_in[0];
  const float* K = (const float*)d_in[1];
  const float* V = (const float*)d_in[2];
  float* O = (float*)d_out;
  (void)in_sizes; (void)n_in; (void)out_size; (void)d_ws; (void)ws_size;
  fattn<<<dim3(B_ * (N_ / NBLK)), dim3(512), 0, stream>>>(Q, K, V, O);
}

// Round 3
// 613.018 us; speedup vs baseline: 2.6748x; 2.6748x over previous
//
#include <hip/hip_runtime.h>
#include <hip/hip_bf16.h>
#include <stdint.h>

#define B_ 8
#define N_ 4096
#define T_ 512
#define M_ 4096
#define KVB 32
#define NBLK 64
#define NT 128          // M_/KVB tiles
#define KT_F16 (KVB*T_) // f16 elems per K tile (32KB)
#define VT_F16 (T_*KVB) // f16 elems per V tile (32KB)

typedef _Float16 f16;
typedef __attribute__((ext_vector_type(8))) f16 f16x8;
typedef __attribute__((ext_vector_type(4))) f16 f16x4;
typedef __attribute__((ext_vector_type(4))) float f32x4;

__device__ __forceinline__ void gld16(const void* g, void* l) {
  __builtin_amdgcn_global_load_lds(
      (const __attribute__((address_space(1))) unsigned int*)g,
      (__attribute__((address_space(3))) unsigned int*)l, 16, 0, 0);
}

// ---------------- pack kernels (write LDS tile byte-images into ws) ----------------
// K image: per tile [m 0..31][stored-chunk s 0..63] (16B chunks, row = 1KB):
//   stored s holds fp16 K[b][t = (s^(m&7))*8 .. +8][m0+m]   (transposed + swizzled)
__global__ __launch_bounds__(256) void pack_k(const float* __restrict__ Kg,
                                              f16* __restrict__ pk) {
  const int bx = blockIdx.x;
  const int ts = bx & 7;            // 64-t slab
  const int mt = (bx >> 3) & (NT - 1);
  const int b  = bx >> 10;
  const int m0 = mt * KVB;
  const int tid = threadIdx.x;
  __shared__ float tileT[64][33];   // [t_local][m]
  {
    const int tl = tid >> 2;
    const int mseg = (tid & 3) * 8;
    const float* src = Kg + (size_t)(b * T_ + ts * 64 + tl) * M_ + m0 + mseg;
    const float4 a = *reinterpret_cast<const float4*>(src);
    const float4 c = *reinterpret_cast<const float4*>(src + 4);
    tileT[tl][mseg + 0] = a.x; tileT[tl][mseg + 1] = a.y;
    tileT[tl][mseg + 2] = a.z; tileT[tl][mseg + 3] = a.w;
    tileT[tl][mseg + 4] = c.x; tileT[tl][mseg + 5] = c.y;
    tileT[tl][mseg + 6] = c.z; tileT[tl][mseg + 7] = c.w;
  }
  __syncthreads();
  {
    const int m  = tid >> 3;
    const int jl = tid & 7;                 // stored chunk (local in slab)
    const int tlc = (jl ^ (m & 7)) * 8;     // source t-chunk (local)
    f16x8 o;
    #pragma unroll
    for (int i = 0; i < 8; ++i) o[i] = (f16)tileT[tlc + i][m];
    f16* dst = pk + ((size_t)(b * NT + mt) * KVB + m) * T_ + (ts * 8 + jl) * 8;
    *reinterpret_cast<f16x8*>(dst) = o;
  }
}

// V image: per tile [t 0..511][stored-chunk c 0..3] (16B chunks, row = 64B):
//   stored c holds fp16 V[b][t][m0 + (c^((t>>1)&3))*8 .. +8]
__global__ __launch_bounds__(256) void pack_v(const float* __restrict__ Vg,
                                              f16* __restrict__ pv) {
  const int bx = blockIdx.x;        // b*NT + mt
  const int mt = bx & (NT - 1);
  const int b  = bx >> 7;
  const int m0 = mt * KVB;
  const int tid = threadIdx.x;
  #pragma unroll
  for (int r = 0; r < 8; ++r) {
    const int task = r * 256 + tid;
    const int t = task >> 2;
    const int c = task & 3;
    const int mc = (c ^ ((t >> 1) & 3)) * 8;
    const float* src = Vg + (size_t)(b * T_ + t) * M_ + m0 + mc;
    const float4 a = *reinterpret_cast<const float4*>(src);
    const float4 d = *reinterpret_cast<const float4*>(src + 4);
    f16x8 o;
    o[0] = (f16)a.x; o[1] = (f16)a.y; o[2] = (f16)a.z; o[3] = (f16)a.w;
    o[4] = (f16)d.x; o[5] = (f16)d.y; o[6] = (f16)d.z; o[7] = (f16)d.w;
    f16* dst = pv + ((size_t)(b * NT + mt) * T_ + t) * KVB + c * 8;
    *reinterpret_cast<f16x8*>(dst) = o;
  }
}

// ---------------- main attention (double-buffered gload_lds staging) ----------------
__global__ __launch_bounds__(512, 2) void fattn(
    const float* __restrict__ Qg, const f16* __restrict__ pk,
    const f16* __restrict__ pv, float* __restrict__ Og)
{
  __shared__ __align__(16) f16 Ks[2][KT_F16];
  __shared__ __align__(16) f16 Vs[2][VT_F16];
  __shared__ __align__(16) f16 Ps[NBLK * KVB];
  __shared__ float redmax[2][NBLK];
  __shared__ float redsum[2][NBLK];
  __shared__ float stat_al[NBLK];
  __shared__ float stat_il[NBLK];

  const int raw = blockIdx.x;
  const int bid = (raw & 7) * 64 + (raw >> 3);   // XCD-chunked: one batch per XCD
  const int b   = bid >> 6;
  const int nb  = (bid & 63) << 6;
  const int tid  = threadIdx.x;
  const int wv   = tid >> 6;
  const int lane = tid & 63;
  const int l15  = lane & 15;
  const int lq   = lane >> 4;
  const int ms   = wv & 1;
  const int ng   = wv >> 1;

  const char* kbase = (const char*)(pk + (size_t)b * NT * KT_F16);
  const char* vbase = (const char*)(pv + (size_t)b * NT * VT_F16);
  const int lo = wv * 1024;

  // stage tile 0 -> buf 0 (overlaps Q load/convert below)
  #pragma unroll
  for (int r = 0; r < 4; ++r) {
    gld16(kbase + r * 8192 + lo + lane * 16, (char*)&Ks[0][0] + r * 8192 + lo);
    gld16(vbase + r * 8192 + lo + lane * 16, (char*)&Vs[0][0] + r * 8192 + lo);
  }

  // Q fragments fp16 hi+lo (split-fp16 QK^T numerics, proven R1)
  f16x8 qh[16], ql[16];
  {
    const float* qrow = Qg + (size_t)(b * N_ + nb + ng * 16 + l15) * T_;
    #pragma unroll
    for (int ks = 0; ks < 16; ++ks) {
      const int k0 = ks * 32 + lq * 8;
      float f[8];
      *reinterpret_cast<float4*>(&f[0]) = *reinterpret_cast<const float4*>(qrow + k0);
      *reinterpret_cast<float4*>(&f[4]) = *reinterpret_cast<const float4*>(qrow + k0 + 4);
      f16x8 h, l;
      #pragma unroll
      for (int j = 0; j < 8; ++j) { h[j] = (f16)f[j]; l[j] = (f16)(f[j] - (float)h[j]); }
      qh[ks] = h; ql[ks] = l;
    }
  }

  f32x4 oacc[4][4];
  #pragma unroll
  for (int tf = 0; tf < 4; ++tf)
    #pragma unroll
    for (int nf = 0; nf < 4; ++nf)
      oacc[tf][nf] = f32x4{0.f, 0.f, 0.f, 0.f};

  float m_run = -INFINITY;
  float l_run = 0.f;

  __syncthreads();   // full waitcnt drain: tile 0 resident

  for (int mt = 0; mt < NT; ++mt) {
    const int cur = mt & 1;

    // issue next-tile staging early (stays in flight across raw barriers B1/B2)
    if (mt + 1 < NT) {
      const char* kt = kbase + (size_t)(mt + 1) * (KT_F16 * 2);
      const char* vt = vbase + (size_t)(mt + 1) * (VT_F16 * 2);
      char* kd = (char*)&Ks[cur ^ 1][0];
      char* vd = (char*)&Vs[cur ^ 1][0];
      #pragma unroll
      for (int r = 0; r < 4; ++r) {
        gld16(kt + r * 8192 + lo + lane * 16, kd + r * 8192 + lo);
        gld16(vt + r * 8192 + lo + lane * 16, vd + r * 8192 + lo);
      }
    }

    // ---- S^T: sacc[reg] = S[m = ms*16+lq*4+reg][n = ng*16+l15]
    f32x4 sacc = f32x4{0.f, 0.f, 0.f, 0.f};
    {
      const f16* KsC = &Ks[cur][0];
      const int mrow = ms * 16 + l15;
      const int mb2 = mrow * T_;
      const int mx = mrow & 7;
      #pragma unroll
      for (int ks = 0; ks < 16; ++ks) {
        const int c = ((ks << 2) + lq) ^ mx;
        const f16x8 a = *reinterpret_cast<const f16x8*>(KsC + mb2 + c * 8);
        sacc = __builtin_amdgcn_mfma_f32_16x16x32_f16(a, qh[ks], sacc, 0, 0, 0);
        sacc = __builtin_amdgcn_mfma_f32_16x16x32_f16(a, ql[ks], sacc, 0, 0, 0);
      }
    }

    // ---- online softmax (split across ms pair)
    const int n = ng * 16 + l15;
    float tmax = fmaxf(fmaxf(sacc[0], sacc[1]), fmaxf(sacc[2], sacc[3]));
    tmax = fmaxf(tmax, __shfl_xor(tmax, 16));
    tmax = fmaxf(tmax, __shfl_xor(tmax, 32));
    if (lane < 16) redmax[ms][ng * 16 + lane] = tmax;
    asm volatile("s_waitcnt lgkmcnt(0)" ::: "memory");   // own ds_write committed
    __builtin_amdgcn_s_barrier();                        // B1 (vmcnt stays live)
    __builtin_amdgcn_sched_barrier(0);

    const float gmax = fmaxf(redmax[0][n], redmax[1][n]);
    const float mnew = fmaxf(m_run, gmax);
    const float alpha = __expf(m_run - mnew);
    if (ms == 0 && lane < 16) stat_al[ng * 16 + lane] = alpha;
    const float p0 = __expf(sacc[0] - mnew);
    const float p1 = __expf(sacc[1] - mnew);
    const float p2 = __expf(sacc[2] - mnew);
    const float p3 = __expf(sacc[3] - mnew);
    float psum = (p0 + p1) + (p2 + p3);
    psum += __shfl_xor(psum, 16);
    psum += __shfl_xor(psum, 32);
    if (lane < 16) redsum[ms][ng * 16 + lane] = psum;
    {
      f16x4 pw;
      pw[0] = (f16)p0; pw[1] = (f16)p1; pw[2] = (f16)p2; pw[3] = (f16)p3;
      const int ch = (ms * 2 + (lq >> 1)) ^ ((n >> 1) & 3);
      *reinterpret_cast<f16x4*>(&Ps[n * KVB + ch * 8 + (lq & 1) * 4]) = pw;
    }
    asm volatile("s_waitcnt lgkmcnt(0)" ::: "memory");
    __builtin_amdgcn_s_barrier();                        // B2
    __builtin_amdgcn_sched_barrier(0);

    l_run = l_run * alpha + redsum[0][n] + redsum[1][n];
    m_run = mnew;

    // ---- PV: rescale O^T, then O^T[t][n] += V[t][m] * P^T[m][n]
    #pragma unroll
    for (int nf = 0; nf < 4; ++nf) {
      const float av = stat_al[nf * 16 + l15];
      #pragma unroll
      for (int tf = 0; tf < 4; ++tf) {
        oacc[tf][nf][0] *= av; oacc[tf][nf][1] *= av;
        oacc[tf][nf][2] *= av; oacc[tf][nf][3] *= av;
      }
    }
    {
      f16x8 vfr[4];
      #pragma unroll
      for (int tf = 0; tf < 4; ++tf) {
        const int t = wv * 64 + tf * 16 + l15;
        vfr[tf] = *reinterpret_cast<const f16x8*>(
            &Vs[cur][t * KVB + (lq ^ ((t >> 1) & 3)) * 8]);
      }
      #pragma unroll
      for (int nf = 0; nf < 4; ++nf) {
        const int n2 = nf * 16 + l15;
        const f16x8 pfr = *reinterpret_cast<const f16x8*>(
            &Ps[n2 * KVB + (lq ^ ((n2 >> 1) & 3)) * 8]);
        #pragma unroll
        for (int tf = 0; tf < 4; ++tf)
          oacc[tf][nf] = __builtin_amdgcn_mfma_f32_16x16x32_f16(vfr[tf], pfr, oacc[tf][nf], 0, 0, 0);
      }
    }
    __syncthreads();   // B3: full drain (next tile resident in buf cur^1)
  }

  // ---- epilogue
  if (ms == 0 && lane < 16) stat_il[ng * 16 + lane] = 1.0f / l_run;
  __syncthreads();
  #pragma unroll
  for (int nf = 0; nf < 4; ++nf) {
    const float il = stat_il[nf * 16 + l15];
    const size_t base = (size_t)(b * N_ + nb + nf * 16 + l15) * T_;
    #pragma unroll
    for (int tf = 0; tf < 4; ++tf) {
      const int t = wv * 64 + tf * 16 + lq * 4;
      float4 o;
      o.x = oacc[tf][nf][0] * il;
      o.y = oacc[tf][nf][1] * il;
      o.z = oacc[tf][nf][2] * il;
      o.w = oacc[tf][nf][3] * il;
      *reinterpret_cast<float4*>(Og + base + t) = o;
    }
  }
}

// ---------------- fallback: round-1 kernel (no ws needed), proven pass ----------------
#define KSTR 520
#define PSTR 48
__global__ __launch_bounds__(512, 2) void fattn_fb(
    const float* __restrict__ Qg, const float* __restrict__ Kg,
    const float* __restrict__ Vg, float* __restrict__ Og)
{
  __shared__ __align__(16) f16 Ksf[KVB * KSTR];
  __shared__ __align__(16) f16 Vsf[T_ * KVB];
  __shared__ __align__(16) f16 Psf[NBLK * PSTR];
  __shared__ float redmax[2][NBLK];
  __shared__ float redsum[2][NBLK];
  __shared__ float stat_al[NBLK];
  __shared__ float stat_il[NBLK];

  const int bid  = blockIdx.x;
  const int b    = bid >> 6;
  const int nb   = (bid & 63) << 6;
  const int tid  = threadIdx.x;
  const int w    = tid >> 6;
  const int lane = tid & 63;
  const int l15  = lane & 15;
  const int lq   = lane >> 4;
  const int ms   = w & 1;
  const int ng   = w >> 1;

  f16x8 qh[16], ql[16];
  {
    const float* qrow = Qg + (size_t)(b * N_ + nb + ng * 16 + l15) * T_;
    #pragma unroll
    for (int ks = 0; ks < 16; ++ks) {
      const int k0 = ks * 32 + lq * 8;
      float f[8];
      *reinterpret_cast<float4*>(&f[0]) = *reinterpret_cast<const float4*>(qrow + k0);
      *reinterpret_cast<float4*>(&f[4]) = *reinterpret_cast<const float4*>(qrow + k0 + 4);
      f16x8 h, l;
      #pragma unroll
      for (int j = 0; j < 8; ++j) { h[j] = (f16)f[j]; l[j] = (f16)(f[j] - (float)h[j]); }
      qh[ks] = h; ql[ks] = l;
    }
  }
  f32x4 oacc[4][4];
  #pragma unroll
  for (int tf = 0; tf < 4; ++tf)
    #pragma unroll
    for (int nf = 0; nf < 4; ++nf)
      oacc[tf][nf] = f32x4{0.f, 0.f, 0.f, 0.f};
  float m_run = -INFINITY, l_run = 0.f;

  for (int mt = 0; mt < M_ / KVB; ++mt) {
    const int m0 = mt * KVB;
    #pragma unroll
    for (int r = 0; r < 8; ++r) {
      const int task = r * 512 + tid;
      const int m  = task & 31;
      const int t0 = (task >> 5) << 2;
      const float* src = Kg + (size_t)(b * T_ + t0) * M_ + m0 + m;
      f16x4 kk;
      kk[0] = (f16)src[0]; kk[1] = (f16)src[M_];
      kk[2] = (f16)src[2 * M_]; kk[3] = (f16)src[3 * M_];
      *reinterpret_cast<f16x4*>(&Ksf[m * KSTR + t0]) = kk;
    }
    #pragma unroll
    for (int r = 0; r < 4; ++r) {
      const int idx = r * 512 + tid;
      const int t  = idx >> 2;
      const int mc = (idx & 3) << 3;
      const float* src = Vg + (size_t)(b * T_ + t) * M_ + m0 + mc;
      const float4 f0 = *reinterpret_cast<const float4*>(src);
      const float4 f1 = *reinterpret_cast<const float4*>(src + 4);
      f16x8 v8;
      v8[0] = (f16)f0.x; v8[1] = (f16)f0.y; v8[2] = (f16)f0.z; v8[3] = (f16)f0.w;
      v8[4] = (f16)f1.x; v8[5] = (f16)f1.y; v8[6] = (f16)f1.z; v8[7] = (f16)f1.w;
      *reinterpret_cast<f16x8*>(&Vsf[t * KVB + (mc ^ ((t & 3) << 3))]) = v8;
    }
    __syncthreads();
    f32x4 sacc = f32x4{0.f, 0.f, 0.f, 0.f};
    {
      const int abase = (ms * 16 + l15) * KSTR + lq * 8;
      #pragma unroll
      for (int ks = 0; ks < 16; ++ks) {
        const f16x8 a = *reinterpret_cast<const f16x8*>(&Ksf[abase + ks * 32]);
        sacc = __builtin_amdgcn_mfma_f32_16x16x32_f16(a, qh[ks], sacc, 0, 0, 0);
        sacc = __builtin_amdgcn_mfma_f32_16x16x32_f16(a, ql[ks], sacc, 0, 0, 0);
      }
    }
    const int n = ng * 16 + l15;
    float tmax = fmaxf(fmaxf(sacc[0], sacc[1]), fmaxf(sacc[2], sacc[3]));
    tmax = fmaxf(tmax, __shfl_xor(tmax, 16));
    tmax = fmaxf(tmax, __shfl_xor(tmax, 32));
    if (lane < 16) redmax[ms][ng * 16 + lane] = tmax;
    __syncthreads();
    const float gmax = fmaxf(redmax[0][n], redmax[1][n]);
    const float mnew = fmaxf(m_run, gmax);
    const float alpha = __expf(m_run - mnew);
    if (ms == 0 && lane < 16) stat_al[ng * 16 + lane] = alpha;
    const float p0 = __expf(sacc[0] - mnew);
    const float p1 = __expf(sacc[1] - mnew);
    const float p2 = __expf(sacc[2] - mnew);
    const float p3 = __expf(sacc[3] - mnew);
    float psum = (p0 + p1) + (p2 + p3);
    psum += __shfl_xor(psum, 16);
    psum += __shfl_xor(psum, 32);
    if (lane < 16) redsum[ms][ng * 16 + lane] = psum;
    {
      f16x4 pw;
      pw[0] = (f16)p0; pw[1] = (f16)p1; pw[2] = (f16)p2; pw[3] = (f16)p3;
      *reinterpret_cast<f16x4*>(&Psf[n * PSTR + ms * 16 + lq * 4]) = pw;
    }
    __syncthreads();
    l_run = l_run * alpha + redsum[0][n] + redsum[1][n];
    m_run = mnew;
    #pragma unroll
    for (int nf = 0; nf < 4; ++nf) {
      const float av = stat_al[nf * 16 + l15];
      #pragma unroll
      for (int tf = 0; tf < 4; ++tf) {
        oacc[tf][nf][0] *= av; oacc[tf][nf][1] *= av;
        oacc[tf][nf][2] *= av; oacc[tf][nf][3] *= av;
      }
    }
    {
      f16x8 vfr[4];
      #pragma unroll
      for (int tf = 0; tf < 4; ++tf) {
        const int t = w * 64 + tf * 16 + l15;
        vfr[tf] = *reinterpret_cast<const f16x8*>(&Vsf[t * KVB + ((lq * 8) ^ ((t & 3) << 3))]);
      }
      #pragma unroll
      for (int nf = 0; nf < 4; ++nf) {
        const f16x8 pfr = *reinterpret_cast<const f16x8*>(&Psf[(nf * 16 + l15) * PSTR + lq * 8]);
        #pragma unroll
        for (int tf = 0; tf < 4; ++tf)
          oacc[tf][nf] = __builtin_amdgcn_mfma_f32_16x16x32_f16(vfr[tf], pfr, oacc[tf][nf], 0, 0, 0);
      }
    }
    __syncthreads();
  }
  if (ms == 0 && lane < 16) stat_il[ng * 16 + lane] = 1.0f / l_run;
  __syncthreads();
  #pragma unroll
  for (int nf = 0; nf < 4; ++nf) {
    const float il = stat_il[nf * 16 + l15];
    const size_t base = (size_t)(b * N_ + nb + nf * 16 + l15) * T_;
    #pragma unroll
    for (int tf = 0; tf < 4; ++tf) {
      const int t = w * 64 + tf * 16 + lq * 4;
      float4 o;
      o.x = oacc[tf][nf][0] * il;
      o.y = oacc[tf][nf][1] * il;
      o.z = oacc[tf][nf][2] * il;
      o.w = oacc[tf][nf][3] * il;
      *reinterpret_cast<float4*>(Og + base + t) = o;
    }
  }
}

extern "C" void kernel_launch(void* const* d_in, const int* in_sizes, int n_in,
                              void* d_out, int out_size, void* d_ws, size_t ws_size,
                              hipStream_t stream) {
  const float* Q = (const float*)d_in[0];
  const float* K = (const float*)d_in[1];
  const float* V = (const float*)d_in[2];
  float* O = (float*)d_out;
  (void)in_sizes; (void)n_in; (void)out_size;

  const size_t needed = (size_t)B_ * NT * KT_F16 * 2 * 2;  // pk + pv = 64MB
  if (ws_size >= needed) {
    f16* pk = (f16*)d_ws;
    f16* pv = pk + (size_t)B_ * NT * KT_F16;
    pack_k<<<dim3(B_ * NT * 8), dim3(256), 0, stream>>>(K, pk);
    pack_v<<<dim3(B_ * NT), dim3(256), 0, stream>>>(V, pv);
    fattn<<<dim3(B_ * (N_ / NBLK)), dim3(512), 0, stream>>>(Q, pk, pv, O);
  } else {
    fattn_fb<<<dim3(B_ * (N_ / NBLK)), dim3(512), 0, stream>>>(Q, K, V, O);
  }
}